// Round 7
// baseline (291.624 us; speedup 1.0000x reference)
//
#include <hip/hip_runtime.h>
#include <math.h>

// B=8, C=64, H=W=256. conv_sigma: OC=32, VALID 3x3 -> 254x254 (bf16 MFMA).
// blur: stride 2, reflect pad 1, sigma/kern precomputed by sigma_kernel.
//
// ws layout (float index): acc[0,256) ; kparams [256,288) ; wtb bf16 @ float-ofs 512
//   wtb[tap][oc][ic] (9*32*64 ushorts = 36 KB), ic-contiguous for B-frags.

typedef __attribute__((ext_vector_type(8))) short s8v;   // 8 bf16
typedef __attribute__((ext_vector_type(4))) float f4v;   // 4 f32

static __device__ inline unsigned short f2bf(float f) {
    union { float f; unsigned int u; } v; v.f = f;
    unsigned int u = v.u;
    unsigned int r = u + 0x7FFFu + ((u >> 16) & 1u);
    return (unsigned short)(r >> 16);
}

// pack 2 f32 -> 2 bf16 (RNE) in one instruction; lo = a, hi = b
static __device__ inline unsigned int pk_bf16(float a, float b) {
    unsigned int r;
    asm("v_cvt_pk_bf16_f32 %0, %1, %2" : "=v"(r) : "v"(a), "v"(b));
    return r;
}

// ---------------- prep: zero acc + weights -> bf16 [tap][oc][ic] ----------------
__global__ void prep_kernel(const float* __restrict__ w, float* __restrict__ ws) {
    int i = blockIdx.x * blockDim.x + threadIdx.x;
    if (i < 256) ws[i] = 0.f;
    if (i < 9 * 32 * 64) {
        int ic  = i & 63;
        int oc  = (i >> 6) & 31;
        int tap = i >> 11;
        unsigned short* wtb = (unsigned short*)(ws + 512);
        wtb[i] = f2bf(w[oc * 576 + ic * 9 + tap]);
    }
}

// ---------------- conv 3x3 VALID (bf16 MFMA) + relu + spatial reduce ----------------
// grid (8 bx, 16 byg, 8 b), block 256 = 4 waves; persistent over 4 y-tiles of
// 4 output rows each (16 rows/block). DOUBLE-BUFFERED LDS: per tile, stage
// tile t+1 into slab-alt in the SAME barrier-free region as tile t's K-loop
// on slab-cur -> scheduler overlaps HBM latency with MFMA/ds_read; one
// __syncthreads per tile. (r6 lesson: barrier-separated burst staging leaves
// HBM at ~37% duty; r5 lesson: reg-held prefetch spills — LDS holds it here.)
// Slab: 6 rows x 37 px x 64 ic bf16 = 27.75 KB, XOR-swizzled 16B chunks
// (slot = ic_oct ^ ((p>>1)&7); read side 2 lanes/bank = free per m136).
__global__ __launch_bounds__(256, 2) void conv_mfma_kernel(
        const float* __restrict__ x, const unsigned short* __restrict__ wtb,
        float* __restrict__ acc_out) {
    __shared__ __align__(16) unsigned char sx[2][222 * 128];  // 2 x 28416 B
    __shared__ float sred[4][32];

    const int bx = blockIdx.x, byg = blockIdx.y, b = blockIdx.z;
    const int ox0 = bx * 32;
    const int tid = threadIdx.x;
    const int lane = tid & 63, w = tid >> 6;
    const int m = lane & 15, q = lane >> 4;
    const float* xb = x + (size_t)b * 64 * 65536;

    // per-thread stage-item constants (tile-invariant)
    // item i -> ch = i%9 (fastest: coalesced), yy = (i/9)%6, r4 = i/54 (ic quad)
    int xc_[4], yy_[4], p0_[4], r4_[4];
    bool vld_[4];
#pragma unroll
    for (int k = 0; k < 4; ++k) {
        int i  = tid + k * 256;
        int ch = i % 9;
        int t9 = i / 9;
        yy_[k] = t9 % 6;
        r4_[k] = (t9 / 6) & 15;
        int xc = ox0 + ch * 4;  if (xc > 252) xc = 252;
        xc_[k] = xc;
        p0_[k] = yy_[k] * 37 + ch * 4;
        vld_[k] = (i < 864);
    }

    // stage one 6-row tile into dst slab (clamped slots feed masked outputs)
#define STAGE(dst, OY0)                                                        \
    {                                                                          \
        _Pragma("unroll")                                                      \
        for (int k = 0; k < 4; ++k) {                                          \
            if (vld_[k]) {                                                     \
                int y = (OY0) + yy_[k];  if (y > 255) y = 255;                 \
                const float* src = xb + ((size_t)r4_[k] << 2) * 65536          \
                                      + y * 256 + xc_[k];                      \
                float4 v0 = *(const float4*)(src);                             \
                float4 v1 = *(const float4*)(src + 65536);                     \
                float4 v2 = *(const float4*)(src + 131072);                    \
                float4 v3 = *(const float4*)(src + 196608);                    \
                const float* a0 = (const float*)&v0;                           \
                const float* a1 = (const float*)&v1;                           \
                const float* a2 = (const float*)&v2;                           \
                const float* a3 = (const float*)&v3;                           \
                int r4 = r4_[k];                                               \
                _Pragma("unroll")                                              \
                for (int j = 0; j < 4; ++j) {                                  \
                    int p = p0_[k] + j;                                        \
                    unsigned int lo = pk_bf16(a0[j], a1[j]);                   \
                    unsigned int hi = pk_bf16(a2[j], a3[j]);                   \
                    int cw = (r4 >> 1) ^ ((p >> 1) & 7);                       \
                    *(uint2*)((dst) + p * 128 + cw * 16 + (r4 & 1) * 8) =      \
                        make_uint2(lo, hi);                                    \
                }                                                              \
            }                                                                  \
        }                                                                      \
    }

    // B-frag preload (tap 0); rotates mod 9 -> holds tap 0 again each tile.
    const unsigned short* wB = wtb + m * 64 + q * 8;
    s8v bc0 = *(const s8v*)(wB);               // kc0, oc m
    s8v bc1 = *(const s8v*)(wB + 1024);        // kc0, oc 16+m
    s8v bc2 = *(const s8v*)(wB + 32);          // kc1, oc m
    s8v bc3 = *(const s8v*)(wB + 1024 + 32);   // kc1, oc 16+m

    // ---- prologue: stage tile 0 ----
    STAGE(sx[0], byg * 16)
    __syncthreads();

    int pb[2];
#pragma unroll
    for (int mt = 0; mt < 2; ++mt)
        pb[mt] = w * 37 + mt * 16 + m;

    float s0 = 0.f, s1 = 0.f;

#pragma unroll
    for (int t = 0; t < 4; ++t) {
        const int oy0 = byg * 16 + t * 4;
        unsigned char* cur = sx[t & 1];
        unsigned char* alt = sx[(t & 1) ^ 1];

        // ---- stage tile t+1 into alt slab (barrier-free vs K-loop below) ----
        if (t < 3) STAGE(alt, oy0 + 4)

        // ---- K-loop tile t: 9 taps, B-frags 2-deep pipelined (mod 9) ----
        f4v acc[2][2];
#pragma unroll
        for (int mt = 0; mt < 2; ++mt)
#pragma unroll
            for (int nt = 0; nt < 2; ++nt) acc[mt][nt] = (f4v)0.f;

#pragma unroll
        for (int tp = 0; tp < 9; ++tp) {
            const int off = (tp / 3) * 37 + (tp % 3);
            const unsigned short* wN = wB + ((tp + 1) % 9) * 2048;
            s8v bn0 = *(const s8v*)(wN);
            s8v bn1 = *(const s8v*)(wN + 1024);
            s8v bn2 = *(const s8v*)(wN + 32);
            s8v bn3 = *(const s8v*)(wN + 1024 + 32);
#pragma unroll
            for (int mt = 0; mt < 2; ++mt) {
                int p  = pb[mt] + off;
                int q0 = q ^ ((p >> 1) & 7);
                s8v afr = *(const s8v*)(cur + p * 128 + q0 * 16);
                acc[mt][0] = __builtin_amdgcn_mfma_f32_16x16x32_bf16(afr, bc0, acc[mt][0], 0, 0, 0);
                acc[mt][1] = __builtin_amdgcn_mfma_f32_16x16x32_bf16(afr, bc1, acc[mt][1], 0, 0, 0);
            }
#pragma unroll
            for (int mt = 0; mt < 2; ++mt) {
                int p  = pb[mt] + off;
                int q1 = (4 + q) ^ ((p >> 1) & 7);
                s8v afr = *(const s8v*)(cur + p * 128 + q1 * 16);
                acc[mt][0] = __builtin_amdgcn_mfma_f32_16x16x32_bf16(afr, bc2, acc[mt][0], 0, 0, 0);
                acc[mt][1] = __builtin_amdgcn_mfma_f32_16x16x32_bf16(afr, bc3, acc[mt][1], 0, 0, 0);
            }
            bc0 = bn0; bc1 = bn1; bc2 = bn2; bc3 = bn3;
        }

        // ---- per-tile epilogue: relu + mask + accumulate ----
        // D layout: col(oc) = lane&15, row(pixel-x) = (lane>>4)*4 + reg
        const int oy = oy0 + w;
#pragma unroll
        for (int mt = 0; mt < 2; ++mt) {
            int oxb = ox0 + mt * 16 + q * 4;
#pragma unroll
            for (int reg = 0; reg < 4; ++reg) {
                bool val = (oxb + reg < 254) && (oy < 254);
                if (val) {
                    s0 += fmaxf(acc[mt][0][reg], 0.f);
                    s1 += fmaxf(acc[mt][1][reg], 0.f);
                }
            }
        }

        __syncthreads();   // alt writes visible + cur reads done, once per tile
    }
#undef STAGE

    // ---- final reduce ----
    s0 += __shfl_xor(s0, 16, 64); s0 += __shfl_xor(s0, 32, 64);
    s1 += __shfl_xor(s1, 16, 64); s1 += __shfl_xor(s1, 32, 64);
    if (lane < 16) { sred[w][lane] = s0; sred[w][16 + lane] = s1; }
    __syncthreads();
    if (tid < 32)
        atomicAdd(&acc_out[b * 32 + tid],
                  sred[0][tid] + sred[1][tid] + sred[2][tid] + sred[3][tid]);
}

// ---------------- sigma tail: fc + sigmoid + gaussian taps, once per batch ----------------
// 1 block x 64 threads: 8 lanes per b reduce the 32-wide fc dot.
__global__ void sigma_kernel(const float* __restrict__ acc, const float* __restrict__ wfc,
                             const float* __restrict__ bfc, float* __restrict__ kout) {
    int t = threadIdx.x;
    int b = t >> 3, j = t & 7;
    float s = 0.f;
#pragma unroll
    for (int i = 0; i < 4; ++i) s += acc[b * 32 + j + i * 8] * wfc[j + i * 8];
    s += __shfl_xor(s, 4, 8);
    s += __shfl_xor(s, 2, 8);
    s += __shfl_xor(s, 1, 8);
    if (j == 0) {
        float z = s * (1.0f / (254.0f * 254.0f)) + bfc[0];
        float sig = 1.0f / (1.0f + __expf(-z));
        float ss = fmaxf(sig, 1e-4f);
        float inv2 = 0.5f / (ss * ss);
        float e1 = __expf(-inv2);
        float e2 = __expf(-2.0f * inv2);
        float inv_norm = 1.0f / (1.0f + 4.0f * e1 + 4.0f * e2);
        kout[b * 4 + 0] = inv_norm;           // center
        kout[b * 4 + 1] = e1 * inv_norm;      // edge
        kout[b * 4 + 2] = e2 * inv_norm;      // diagonal
    }
}

// ---------------- blur: stride-2 3x3 with precomputed taps ----------------
// grid (16 oy-blocks, 8 b, 64 c), block 256 = 32 x-threads x 8 oy.
__global__ __launch_bounds__(256) void blur_kernel(
        const float* __restrict__ x, const float* __restrict__ kp,
        float* __restrict__ out) {
    const int c = blockIdx.z, b = blockIdx.y;
    const int tid = threadIdx.x;
    const int qx = tid & 31;                 // 4-output group
    const int oy = blockIdx.x * 8 + (tid >> 5);

    const float kC = kp[b * 4 + 0];
    const float kE = kp[b * 4 + 1];
    const float kD = kp[b * 4 + 2];

    const float* xb = x + ((size_t)(b * 64 + c)) * 65536;

    float o0 = 0.f, o1 = 0.f, o2 = 0.f, o3 = 0.f;
#pragma unroll
    for (int dy = 0; dy < 3; ++dy) {
        int iy = 2 * oy + dy - 1;
        if (iy < 0) iy = 1;                   // reflect
        const float* row = xb + iy * 256;
        const float4 f0 = *(const float4*)(row + 8 * qx);
        const float4 f1 = *(const float4*)(row + 8 * qx + 4);
        float lf = __shfl_up(f1.w, 1, 64);    // left neighbor's last element
        const float sm1 = (qx == 0) ? f0.y : lf;   // reflect at x=-1 -> x=1
        const float ka = (dy == 1) ? kE : kD;
        const float kb = (dy == 1) ? kC : kE;
        const float kc2 = (dy == 1) ? kE : kD;
        o0 = fmaf(ka, sm1,  fmaf(kb, f0.x, fmaf(kc2, f0.y, o0)));
        o1 = fmaf(ka, f0.y, fmaf(kb, f0.z, fmaf(kc2, f0.w, o1)));
        o2 = fmaf(ka, f0.w, fmaf(kb, f1.x, fmaf(kc2, f1.y, o2)));
        o3 = fmaf(ka, f1.y, fmaf(kb, f1.z, fmaf(kc2, f1.w, o3)));
    }
    *(float4*)(out + (((size_t)c * 8 + b) * 128 + oy) * 128 + 4 * qx) =
        make_float4(o0, o1, o2, o3);
}

extern "C" void kernel_launch(void* const* d_in, const int* in_sizes, int n_in,
                              void* d_out, int out_size, void* d_ws, size_t ws_size,
                              hipStream_t stream) {
    const float* x       = (const float*)d_in[0];
    const float* w_sigma = (const float*)d_in[1];
    const float* w_fc    = (const float*)d_in[2];
    const float* b_fc    = (const float*)d_in[3];
    float* out = (float*)d_out;
    float* ws  = (float*)d_ws;
    const unsigned short* wtb = (const unsigned short*)(ws + 512);

    prep_kernel<<<72, 256, 0, stream>>>(w_sigma, ws);
    conv_mfma_kernel<<<dim3(8, 16, 8), 256, 0, stream>>>(x, wtb, ws);
    sigma_kernel<<<1, 64, 0, stream>>>(ws, w_fc, b_fc, ws + 256);
    blur_kernel<<<dim3(16, 8, 64), 256, 0, stream>>>(x, ws + 256, out);
}

// Round 8
// 253.943 us; speedup vs baseline: 1.1484x; 1.1484x over previous
//
#include <hip/hip_runtime.h>
#include <math.h>

// B=8, C=64, H=W=256. conv_sigma: OC=32, VALID 3x3 -> 254x254 (bf16 MFMA).
// blur: stride 2, reflect pad 1, sigma/kern precomputed by sigma_kernel.
//
// ws layout (float index): acc[0,256) ; kparams [256,288) ; wtb bf16 @ float-ofs 512
//   wtb[tap][oc][ic] (9*32*64 ushorts = 36 KB), ic-contiguous for B-frags.

typedef __attribute__((ext_vector_type(8))) short s8v;   // 8 bf16
typedef __attribute__((ext_vector_type(4))) float f4v;   // 4 f32

static __device__ inline unsigned short f2bf(float f) {
    union { float f; unsigned int u; } v; v.f = f;
    unsigned int u = v.u;
    unsigned int r = u + 0x7FFFu + ((u >> 16) & 1u);
    return (unsigned short)(r >> 16);
}

// pack 2 f32 -> 2 bf16 (RNE) in one instruction; lo = a, hi = b
static __device__ inline unsigned int pk_bf16(float a, float b) {
    unsigned int r;
    asm("v_cvt_pk_bf16_f32 %0, %1, %2" : "=v"(r) : "v"(a), "v"(b));
    return r;
}

// volatile asm dwordx4 load: cannot be sunk/reordered vs other volatile asm.
static __device__ inline float4 ld128(const float* p) {
    float4 d;
    asm volatile("global_load_dwordx4 %0, %1, off"
                 : "=v"(d) : "v"(p));
    return d;
}

// ---------------- prep: zero acc + weights -> bf16 [tap][oc][ic] ----------------
__global__ void prep_kernel(const float* __restrict__ w, float* __restrict__ ws) {
    int i = blockIdx.x * blockDim.x + threadIdx.x;
    if (i < 256) ws[i] = 0.f;
    if (i < 9 * 32 * 64) {
        int ic  = i & 63;
        int oc  = (i >> 6) & 31;
        int tap = i >> 11;
        unsigned short* wtb = (unsigned short*)(ws + 512);
        wtb[i] = f2bf(w[oc * 576 + ic * 9 + tap]);
    }
}

// ---------------- conv 3x3 VALID (bf16 MFMA) + relu + spatial reduce ----------------
// grid (8 bx, 32 by, 8 b), block 256 = 4 waves. Block: 8 oy x 32 ox x 32 oc.
// LDS slab: 10 rows x 37 px x 64 ic bf16, [pixel][ic], XOR-swizzled 16B chunks
// (slot = ic_oct ^ ((p>>1)&7); read side 2 lanes/bank = free per m136).
//
// Staging concurrency (r1-r7 lesson): compiler-scheduled loads keep only ~1KB
// in flight/wave (loads sunk to uses; VGPR stayed 68) -> 1.5 TB/s plateau.
// Fix: VOLATILE inline-asm global_load_dwordx4 x24 (order-pinned), one
// s_waitcnt vmcnt(0), sched_barrier(0) (rule #18) -> 24KB in flight/wave.
__global__ __launch_bounds__(256, 3) void conv_mfma_kernel(
        const float* __restrict__ x, const unsigned short* __restrict__ wtb,
        float* __restrict__ acc_out) {
    __shared__ __align__(16) unsigned char sx[370 * 128];  // 47360 B
    __shared__ float sred[4][32];

    const int bx = blockIdx.x, by = blockIdx.y, b = blockIdx.z;
    const int ox0 = bx * 32, oy0 = by * 8;
    const int tid = threadIdx.x;
    const int lane = tid & 63, w = tid >> 6;
    const int m = lane & 15, q = lane >> 4;

    // ---- stage phase 1: issue ALL 24 dwordx4 via volatile asm ----
    // item i -> ch = i%9 (fastest: coalesced), yy = (i/9)%10, r4 = i/90 (ic quad)
    // Addresses clamped in-bounds; clamped slots feed only epilogue-masked outputs.
    const float* xb = x + (size_t)b * 64 * 65536;
    float4 va[6][4];
    int   pj[6];
    int   r4a[6];
    bool  vld[6];
#pragma unroll
    for (int k = 0; k < 6; ++k) {
        int i  = tid + k * 256;
        int ch = i % 9;
        int t9 = i / 9;
        int yy = t9 % 10;
        int r4 = (t9 / 10) & 15;
        int y  = oy0 + yy;  if (y > 255) y = 255;
        int xc = ox0 + ch * 4;  if (xc > 252) xc = 252;
        const float* src = xb + ((size_t)r4 << 2) * 65536 + y * 256 + xc;
        va[k][0] = ld128(src);
        va[k][1] = ld128(src + 65536);
        va[k][2] = ld128(src + 131072);
        va[k][3] = ld128(src + 196608);
        pj[k]  = yy * 37 + ch * 4;
        r4a[k] = r4;
        vld[k] = (i < 1440);
    }

    // ---- B-frag prefetch for tap 0 (normal loads; drain with the batch) ----
    const unsigned short* wB = wtb + m * 64 + q * 8;
    s8v bc0 = *(const s8v*)(wB);               // kc0, oc m
    s8v bc1 = *(const s8v*)(wB + 1024);        // kc0, oc 16+m
    s8v bc2 = *(const s8v*)(wB + 32);          // kc1, oc m
    s8v bc3 = *(const s8v*)(wB + 1024 + 32);   // kc1, oc 16+m

    // ---- drain + scheduling fence (nothing below may move above) ----
    asm volatile("s_waitcnt vmcnt(0)" ::: "memory");
    __builtin_amdgcn_sched_barrier(0);

    // ---- stage phase 2: convert + LDS write ----
#pragma unroll
    for (int k = 0; k < 6; ++k) {
        if (vld[k]) {
            int r4 = r4a[k];
            const float* a0 = (const float*)&va[k][0];
            const float* a1 = (const float*)&va[k][1];
            const float* a2 = (const float*)&va[k][2];
            const float* a3 = (const float*)&va[k][3];
#pragma unroll
            for (int j = 0; j < 4; ++j) {
                int p = pj[k] + j;
                unsigned int lo = pk_bf16(a0[j], a1[j]);   // ic 4r4, 4r4+1
                unsigned int hi = pk_bf16(a2[j], a3[j]);   // ic 4r4+2, 4r4+3
                int cw = (r4 >> 1) ^ ((p >> 1) & 7);
                *(uint2*)(sx + p * 128 + cw * 16 + (r4 & 1) * 8) = make_uint2(lo, hi);
            }
        }
    }
    __syncthreads();

    // ---- K-loop: fully unrolled 9 taps, B-frags 2-deep software pipelined ----
    f4v acc[4][2];
#pragma unroll
    for (int mt = 0; mt < 4; ++mt)
#pragma unroll
        for (int nt = 0; nt < 2; ++nt) acc[mt][nt] = (f4v)0.f;

    int pb[4];
#pragma unroll
    for (int mt = 0; mt < 4; ++mt)
        pb[mt] = (2 * w + (mt >> 1)) * 37 + (mt & 1) * 16 + m;

#pragma unroll
    for (int t = 0; t < 9; ++t) {
        const int off = (t / 3) * 37 + (t % 3);   // compile-time tap offset
        s8v bn0, bn1, bn2, bn3;
        if (t < 8) {                               // compile-time branch
            const unsigned short* wN = wB + (t + 1) * 2048;
            bn0 = *(const s8v*)(wN);
            bn1 = *(const s8v*)(wN + 1024);
            bn2 = *(const s8v*)(wN + 32);
            bn3 = *(const s8v*)(wN + 1024 + 32);
        }
#pragma unroll
        for (int mt = 0; mt < 4; ++mt) {
            int p  = pb[mt] + off;
            int q0 = q ^ ((p >> 1) & 7);
            s8v afr = *(const s8v*)(sx + p * 128 + q0 * 16);
            acc[mt][0] = __builtin_amdgcn_mfma_f32_16x16x32_bf16(afr, bc0, acc[mt][0], 0, 0, 0);
            acc[mt][1] = __builtin_amdgcn_mfma_f32_16x16x32_bf16(afr, bc1, acc[mt][1], 0, 0, 0);
        }
#pragma unroll
        for (int mt = 0; mt < 4; ++mt) {
            int p  = pb[mt] + off;
            int q1 = (4 + q) ^ ((p >> 1) & 7);
            s8v afr = *(const s8v*)(sx + p * 128 + q1 * 16);
            acc[mt][0] = __builtin_amdgcn_mfma_f32_16x16x32_bf16(afr, bc2, acc[mt][0], 0, 0, 0);
            acc[mt][1] = __builtin_amdgcn_mfma_f32_16x16x32_bf16(afr, bc3, acc[mt][1], 0, 0, 0);
        }
        if (t < 8) { bc0 = bn0; bc1 = bn1; bc2 = bn2; bc3 = bn3; }
    }

    // ---- epilogue: relu + mask invalid pixels + reduce ----
    // D layout: col(oc) = lane&15, row(pixel-x) = (lane>>4)*4 + reg
    float s0 = 0.f, s1 = 0.f;
#pragma unroll
    for (int mt = 0; mt < 4; ++mt) {
        int oy = oy0 + 2 * w + (mt >> 1);
        int oxb = ox0 + (mt & 1) * 16 + q * 4;
#pragma unroll
        for (int reg = 0; reg < 4; ++reg) {
            bool val = (oxb + reg < 254) && (oy < 254);
            if (val) {
                s0 += fmaxf(acc[mt][0][reg], 0.f);
                s1 += fmaxf(acc[mt][1][reg], 0.f);
            }
        }
    }
    s0 += __shfl_xor(s0, 16, 64); s0 += __shfl_xor(s0, 32, 64);
    s1 += __shfl_xor(s1, 16, 64); s1 += __shfl_xor(s1, 32, 64);
    if (lane < 16) { sred[w][lane] = s0; sred[w][16 + lane] = s1; }
    __syncthreads();
    if (tid < 32)
        atomicAdd(&acc_out[b * 32 + tid],
                  sred[0][tid] + sred[1][tid] + sred[2][tid] + sred[3][tid]);
}

// ---------------- sigma tail: fc + sigmoid + gaussian taps, once per batch ----------------
// 1 block x 64 threads: 8 lanes per b reduce the 32-wide fc dot.
__global__ void sigma_kernel(const float* __restrict__ acc, const float* __restrict__ wfc,
                             const float* __restrict__ bfc, float* __restrict__ kout) {
    int t = threadIdx.x;
    int b = t >> 3, j = t & 7;
    float s = 0.f;
#pragma unroll
    for (int i = 0; i < 4; ++i) s += acc[b * 32 + j + i * 8] * wfc[j + i * 8];
    s += __shfl_xor(s, 4, 8);
    s += __shfl_xor(s, 2, 8);
    s += __shfl_xor(s, 1, 8);
    if (j == 0) {
        float z = s * (1.0f / (254.0f * 254.0f)) + bfc[0];
        float sig = 1.0f / (1.0f + __expf(-z));
        float ss = fmaxf(sig, 1e-4f);
        float inv2 = 0.5f / (ss * ss);
        float e1 = __expf(-inv2);
        float e2 = __expf(-2.0f * inv2);
        float inv_norm = 1.0f / (1.0f + 4.0f * e1 + 4.0f * e2);
        kout[b * 4 + 0] = inv_norm;           // center
        kout[b * 4 + 1] = e1 * inv_norm;      // edge
        kout[b * 4 + 2] = e2 * inv_norm;      // diagonal
    }
}

// ---------------- blur: stride-2 3x3 with precomputed taps ----------------
// grid (16 oy-blocks, 8 b, 64 c), block 256 = 32 x-threads x 8 oy.
__global__ __launch_bounds__(256) void blur_kernel(
        const float* __restrict__ x, const float* __restrict__ kp,
        float* __restrict__ out) {
    const int c = blockIdx.z, b = blockIdx.y;
    const int tid = threadIdx.x;
    const int qx = tid & 31;                 // 4-output group
    const int oy = blockIdx.x * 8 + (tid >> 5);

    const float kC = kp[b * 4 + 0];
    const float kE = kp[b * 4 + 1];
    const float kD = kp[b * 4 + 2];

    const float* xb = x + ((size_t)(b * 64 + c)) * 65536;

    float o0 = 0.f, o1 = 0.f, o2 = 0.f, o3 = 0.f;
#pragma unroll
    for (int dy = 0; dy < 3; ++dy) {
        int iy = 2 * oy + dy - 1;
        if (iy < 0) iy = 1;                   // reflect
        const float* row = xb + iy * 256;
        const float4 f0 = *(const float4*)(row + 8 * qx);
        const float4 f1 = *(const float4*)(row + 8 * qx + 4);
        float lf = __shfl_up(f1.w, 1, 64);    // left neighbor's last element
        const float sm1 = (qx == 0) ? f0.y : lf;   // reflect at x=-1 -> x=1
        const float ka = (dy == 1) ? kE : kD;
        const float kb = (dy == 1) ? kC : kE;
        const float kc2 = (dy == 1) ? kE : kD;
        o0 = fmaf(ka, sm1,  fmaf(kb, f0.x, fmaf(kc2, f0.y, o0)));
        o1 = fmaf(ka, f0.y, fmaf(kb, f0.z, fmaf(kc2, f0.w, o1)));
        o2 = fmaf(ka, f0.w, fmaf(kb, f1.x, fmaf(kc2, f1.y, o2)));
        o3 = fmaf(ka, f1.y, fmaf(kb, f1.z, fmaf(kc2, f1.w, o3)));
    }
    *(float4*)(out + (((size_t)c * 8 + b) * 128 + oy) * 128 + 4 * qx) =
        make_float4(o0, o1, o2, o3);
}

extern "C" void kernel_launch(void* const* d_in, const int* in_sizes, int n_in,
                              void* d_out, int out_size, void* d_ws, size_t ws_size,
                              hipStream_t stream) {
    const float* x       = (const float*)d_in[0];
    const float* w_sigma = (const float*)d_in[1];
    const float* w_fc    = (const float*)d_in[2];
    const float* b_fc    = (const float*)d_in[3];
    float* out = (float*)d_out;
    float* ws  = (float*)d_ws;
    const unsigned short* wtb = (const unsigned short*)(ws + 512);

    prep_kernel<<<72, 256, 0, stream>>>(w_sigma, ws);
    conv_mfma_kernel<<<dim3(8, 32, 8), 256, 0, stream>>>(x, wtb, ws);
    sigma_kernel<<<1, 64, 0, stream>>>(ws, w_fc, b_fc, ws + 256);
    blur_kernel<<<dim3(16, 8, 64), 256, 0, stream>>>(x, ws + 256, out);
}

// Round 9
// 242.633 us; speedup vs baseline: 1.2019x; 1.0466x over previous
//
#include <hip/hip_runtime.h>
#include <math.h>

// B=8, C=64, H=W=256. conv_sigma: OC=32, VALID 3x3 -> 254x254 (bf16 MFMA).
// blur: stride 2, reflect pad 1, sigma/kern precomputed by sigma_kernel.
//
// r9 redesign: conv reads x in FULL-ROW 1-KB contiguous bursts (one wave-instr
// per (row, ic)), fixing the 144-B access grain that capped every prior
// variant at ~1.5 TB/s (DRAM row-buffer thrash theory; m13 streaming = 6.3).
//
// ws layout (float index): acc[0,256) ; kparams [256,288) ; wtb2 bf16 @ 512:
//   wtb2[icg][tap][oc32][ic32] (2*9*32*32 ushorts = 36 KB).

typedef __attribute__((ext_vector_type(8))) short s8v;   // 8 bf16
typedef __attribute__((ext_vector_type(4))) float f4v;   // 4 f32

static __device__ inline unsigned short f2bf(float f) {
    union { float f; unsigned int u; } v; v.f = f;
    unsigned int u = v.u;
    unsigned int r = u + 0x7FFFu + ((u >> 16) & 1u);
    return (unsigned short)(r >> 16);
}

// pack 2 f32 -> 2 bf16 (RNE) in one instruction; lo = a, hi = b
static __device__ inline unsigned int pk_bf16(float a, float b) {
    unsigned int r;
    asm("v_cvt_pk_bf16_f32 %0, %1, %2" : "=v"(r) : "v"(a), "v"(b));
    return r;
}

// ---------------- prep: zero acc + weights -> bf16 [icg][tap][oc][ic32] ----------------
__global__ void prep_kernel(const float* __restrict__ w, float* __restrict__ ws) {
    int i = blockIdx.x * blockDim.x + threadIdx.x;
    if (i < 256) ws[i] = 0.f;
    if (i < 18432) {
        int icg = i / 9216;
        int rem = i - icg * 9216;
        int tap = rem >> 10;          // 1024 = 32 oc * 32 ic
        int oc  = (rem >> 5) & 31;
        int icl = rem & 31;
        unsigned short* wtb = (unsigned short*)(ws + 512);
        wtb[i] = f2bf(w[oc * 576 + (icg * 32 + icl) * 9 + tap]);
    }
}

// ---------------- conv 3x3 VALID (bf16 MFMA) + relu + spatial reduce ----------------
// grid (127 yp, 8 b), block 256 = 4 waves. Block: 2 out rows (2yp,2yp+1) x
// 254 ox x 32 oc; input rows 2yp..2yp+3, px 0..255 (no clamps anywhere).
// ic split: 2 groups of 32 (K=32 per tap -> 1 MFMA/tap), acc carried across.
// Wave w: out-row w>>1, px half (w&1)*128; 8 M-tiles x 2 N-tiles acc.
//
// LDS 64 KB: 1024 px-rows (4 input rows x 256 px) x 32 ic bf16.
// Chunk space: C = pxrow*4 + ic_octet (16B chunks); stored at C' = C ^ ((C>>4)&7)
// -> b128 frag reads spread all 32 banks (free); b64 stage writes ~2x conflict.
// Stage: item (r, jq=ic-quad): lane covers px 4l..4l+3 -> each of the 4 global
// float4 loads is a 1-KB contiguous wave burst (the whole point of this round).
__global__ __launch_bounds__(256, 2) void conv_mfma_kernel(
        const float* __restrict__ x, const unsigned short* __restrict__ wtb,
        float* __restrict__ acc_out) {
    __shared__ __align__(16) unsigned char sx[65536];
    float* sred = (float*)sx;   // aliased; used only after post-K-loop barrier

    const int yp = blockIdx.x, b = blockIdx.y;
    const int iy0 = 2 * yp;
    const int tid = threadIdx.x;
    const int lane = tid & 63, w = tid >> 6;
    const int m = lane & 15, q = lane >> 4;
    const float* xb = x + (size_t)b * 64 * 65536;

    const int orow = w >> 1;           // wave's output row (0/1)
    const int pxb  = (w & 1) * 128;    // wave's px half

    f4v acc[8][2];
#pragma unroll
    for (int i = 0; i < 8; ++i) {
        acc[i][0] = (f4v)0.f;
        acc[i][1] = (f4v)0.f;
    }

#pragma unroll
    for (int icg = 0; icg < 2; ++icg) {
        if (icg) __syncthreads();      // prior K-loop reads done before restage

        // ---- stage: 32 items (r 0..3, jq 0..7); wave w takes t = 4k+w ----
#pragma unroll
        for (int k = 0; k < 8; ++k) {
            int t  = 4 * k + w;
            int r  = t >> 3;
            int jq = t & 7;
            const float* src = xb + (size_t)(icg * 32 + 4 * jq) * 65536
                                  + (iy0 + r) * 256 + 4 * lane;
            float4 v0 = *(const float4*)(src);            // ic 4jq
            float4 v1 = *(const float4*)(src + 65536);    // ic 4jq+1
            float4 v2 = *(const float4*)(src + 131072);   // ic 4jq+2
            float4 v3 = *(const float4*)(src + 196608);   // ic 4jq+3
            const float* a0 = (const float*)&v0;
            const float* a1 = (const float*)&v1;
            const float* a2 = (const float*)&v2;
            const float* a3 = (const float*)&v3;
#pragma unroll
            for (int u = 0; u < 4; ++u) {
                int pxrow = r * 256 + 4 * lane + u;
                int C = pxrow * 4 + (jq >> 1);
                C ^= (C >> 4) & 7;
                *(uint2*)(sx + C * 16 + (jq & 1) * 8) =
                    make_uint2(pk_bf16(a0[u], a1[u]), pk_bf16(a2[u], a3[u]));
            }
        }

        // ---- tap-0 B-frag prefetch (overlaps barrier) ----
        const unsigned short* wg = wtb + icg * 9216;
        s8v b0 = *(const s8v*)(wg + m * 32 + q * 8);          // oc m
        s8v b1 = *(const s8v*)(wg + (16 + m) * 32 + q * 8);   // oc 16+m
        __syncthreads();

        // ---- K-loop: 9 taps, 1 MFMA/tap/Mtile/Ntile, B-frags 2-deep ----
#pragma unroll
        for (int tp = 0; tp < 9; ++tp) {
            const int dy = tp / 3, dx = tp % 3;
            s8v bn0, bn1;
            if (tp < 8) {
                const unsigned short* wn = wg + (tp + 1) * 1024;
                bn0 = *(const s8v*)(wn + m * 32 + q * 8);
                bn1 = *(const s8v*)(wn + (16 + m) * 32 + q * 8);
            }
#pragma unroll
            for (int i = 0; i < 8; ++i) {
                int prw = (orow + dy) * 256 + pxb + i * 16 + m + dx;
                if (prw > 1023) prw = 1023;     // px 256/257 -> masked outputs only
                int C = prw * 4 + q;
                C ^= (C >> 4) & 7;
                s8v afr = *(const s8v*)(sx + C * 16);
                acc[i][0] = __builtin_amdgcn_mfma_f32_16x16x32_bf16(afr, b0, acc[i][0], 0, 0, 0);
                acc[i][1] = __builtin_amdgcn_mfma_f32_16x16x32_bf16(afr, b1, acc[i][1], 0, 0, 0);
            }
            if (tp < 8) { b0 = bn0; b1 = bn1; }
        }
    }

    // ---- epilogue: relu + mask px>=254 + reduce ----
    // D layout: col(oc) = m, row(px) = q*4 + reg. oy = iy0+orow <= 253 always.
    float s0 = 0.f, s1 = 0.f;
#pragma unroll
    for (int i = 0; i < 8; ++i) {
#pragma unroll
        for (int reg = 0; reg < 4; ++reg) {
            int px = pxb + i * 16 + q * 4 + reg;
            if (px < 254) {
                s0 += fmaxf(acc[i][0][reg], 0.f);
                s1 += fmaxf(acc[i][1][reg], 0.f);
            }
        }
    }
    s0 += __shfl_xor(s0, 16, 64); s0 += __shfl_xor(s0, 32, 64);
    s1 += __shfl_xor(s1, 16, 64); s1 += __shfl_xor(s1, 32, 64);
    __syncthreads();               // all sx frag reads done before aliasing
    if (lane < 16) { sred[w * 32 + lane] = s0; sred[w * 32 + 16 + lane] = s1; }
    __syncthreads();
    if (tid < 32)
        atomicAdd(&acc_out[b * 32 + tid],
                  sred[tid] + sred[32 + tid] + sred[64 + tid] + sred[96 + tid]);
}

// ---------------- sigma tail: fc + sigmoid + gaussian taps, once per batch ----------------
__global__ void sigma_kernel(const float* __restrict__ acc, const float* __restrict__ wfc,
                             const float* __restrict__ bfc, float* __restrict__ kout) {
    int t = threadIdx.x;
    int b = t >> 3, j = t & 7;
    float s = 0.f;
#pragma unroll
    for (int i = 0; i < 4; ++i) s += acc[b * 32 + j + i * 8] * wfc[j + i * 8];
    s += __shfl_xor(s, 4, 8);
    s += __shfl_xor(s, 2, 8);
    s += __shfl_xor(s, 1, 8);
    if (j == 0) {
        float z = s * (1.0f / (254.0f * 254.0f)) + bfc[0];
        float sig = 1.0f / (1.0f + __expf(-z));
        float ss = fmaxf(sig, 1e-4f);
        float inv2 = 0.5f / (ss * ss);
        float e1 = __expf(-inv2);
        float e2 = __expf(-2.0f * inv2);
        float inv_norm = 1.0f / (1.0f + 4.0f * e1 + 4.0f * e2);
        kout[b * 4 + 0] = inv_norm;           // center
        kout[b * 4 + 1] = e1 * inv_norm;      // edge
        kout[b * 4 + 2] = e2 * inv_norm;      // diagonal
    }
}

// ---------------- blur: stride-2 3x3 with precomputed taps ----------------
__global__ __launch_bounds__(256) void blur_kernel(
        const float* __restrict__ x, const float* __restrict__ kp,
        float* __restrict__ out) {
    const int c = blockIdx.z, b = blockIdx.y;
    const int tid = threadIdx.x;
    const int qx = tid & 31;                 // 4-output group
    const int oy = blockIdx.x * 8 + (tid >> 5);

    const float kC = kp[b * 4 + 0];
    const float kE = kp[b * 4 + 1];
    const float kD = kp[b * 4 + 2];

    const float* xb = x + ((size_t)(b * 64 + c)) * 65536;

    float o0 = 0.f, o1 = 0.f, o2 = 0.f, o3 = 0.f;
#pragma unroll
    for (int dy = 0; dy < 3; ++dy) {
        int iy = 2 * oy + dy - 1;
        if (iy < 0) iy = 1;                   // reflect
        const float* row = xb + iy * 256;
        const float4 f0 = *(const float4*)(row + 8 * qx);
        const float4 f1 = *(const float4*)(row + 8 * qx + 4);
        float lf = __shfl_up(f1.w, 1, 64);    // left neighbor's last element
        const float sm1 = (qx == 0) ? f0.y : lf;   // reflect at x=-1 -> x=1
        const float ka = (dy == 1) ? kE : kD;
        const float kb = (dy == 1) ? kC : kE;
        const float kc2 = (dy == 1) ? kE : kD;
        o0 = fmaf(ka, sm1,  fmaf(kb, f0.x, fmaf(kc2, f0.y, o0)));
        o1 = fmaf(ka, f0.y, fmaf(kb, f0.z, fmaf(kc2, f0.w, o1)));
        o2 = fmaf(ka, f0.w, fmaf(kb, f1.x, fmaf(kc2, f1.y, o2)));
        o3 = fmaf(ka, f1.y, fmaf(kb, f1.z, fmaf(kc2, f1.w, o3)));
    }
    *(float4*)(out + (((size_t)c * 8 + b) * 128 + oy) * 128 + 4 * qx) =
        make_float4(o0, o1, o2, o3);
}

extern "C" void kernel_launch(void* const* d_in, const int* in_sizes, int n_in,
                              void* d_out, int out_size, void* d_ws, size_t ws_size,
                              hipStream_t stream) {
    const float* x       = (const float*)d_in[0];
    const float* w_sigma = (const float*)d_in[1];
    const float* w_fc    = (const float*)d_in[2];
    const float* b_fc    = (const float*)d_in[3];
    float* out = (float*)d_out;
    float* ws  = (float*)d_ws;
    const unsigned short* wtb = (const unsigned short*)(ws + 512);

    prep_kernel<<<72, 256, 0, stream>>>(w_sigma, ws);
    conv_mfma_kernel<<<dim3(127, 8), 256, 0, stream>>>(x, wtb, ws);
    sigma_kernel<<<1, 64, 0, stream>>>(ws, w_fc, b_fc, ws + 256);
    blur_kernel<<<dim3(16, 8, 64), 256, 0, stream>>>(x, ws + 256, out);
}